// Round 4
// baseline (147.669 us; speedup 1.0000x reference)
//
#include <hip/hip_runtime.h>
#include <hip/hip_fp16.h>

#define N_NODES 100000
#define CCH 64
#define E_EDGES 1600000
#define HH 8
#define EPT 4   // edges per thread

typedef float v4f __attribute__((ext_vector_type(4)));

// 16-byte per-node record: p[4], q as fp16 (+3 pad) -> one dwordx4 per gather.
// Both tables combined = 3.2 MB -> fits per-XCD 4 MiB L2.
union RecU {
    uint4  v;
    __half h[8];
};

__global__ __launch_bounds__(256) void node_pre(
    const float* __restrict__ x,
    const int* __restrict__ layer_idx_p,
    const float* __restrict__ psi_w,
    const float* __restrict__ psi_b,
    const float* __restrict__ delta_w,
    const float* __restrict__ u,
    uint4* __restrict__ srcRec,
    uint4* __restrict__ dstRec)
{
    __shared__ float4 s_w0[CCH];
    __shared__ float4 s_w1[CCH];
    __shared__ float  s_b0[CCH];
    __shared__ float  s_b1[CCH];

    int li = layer_idx_p[0];
    for (int i = threadIdx.x; i < 2 * CCH; i += blockDim.x) {
        float4 w = make_float4(psi_w[i * 4 + 0], psi_w[i * 4 + 1],
                               psi_w[i * 4 + 2], psi_w[i * 4 + 3]);
        float bb = psi_b[i] + delta_w[li * 2 * CCH + i] + u[li * 2 * CCH + i];
        if (i < CCH) { s_w0[i] = w; s_b0[i] = bb; }
        else         { s_w1[i - CCH] = w; s_b1[i - CCH] = bb; }
    }
    __syncthreads();

    int n = blockIdx.x * blockDim.x + threadIdx.x;
    if (n >= N_NODES) return;

    const float4* xr = (const float4*)(x + (size_t)n * CCH);
    float a0 = 0, a1 = 0, a2 = 0, a3 = 0, aq = 0;
    float c0 = 0, c1 = 0, c2 = 0, c3 = 0, cq = 0;
#pragma unroll
    for (int it = 0; it < CCH / 4; ++it) {
        float4 xv4 = xr[it];
        float xv[4] = { xv4.x, xv4.y, xv4.z, xv4.w };
#pragma unroll
        for (int j = 0; j < 4; ++j) {
            int c = it * 4 + j;
            float xv_ = xv[j];
            float4 w0 = s_w0[c];
            float4 w1 = s_w1[c];
            a0 += xv_ * w0.x; a1 += xv_ * w0.y; a2 += xv_ * w0.z; a3 += xv_ * w0.w;
            aq += xv_ * s_b0[c];
            c0 += xv_ * w1.x; c1 += xv_ * w1.y; c2 += xv_ * w1.z; c3 += xv_ * w1.w;
            cq += xv_ * s_b1[c];
        }
    }
    RecU rs;
    rs.h[0] = __float2half_rn(a0); rs.h[1] = __float2half_rn(a1);
    rs.h[2] = __float2half_rn(a2); rs.h[3] = __float2half_rn(a3);
    rs.h[4] = __float2half_rn(aq);
    rs.h[5] = __half(0.0f); rs.h[6] = __half(0.0f); rs.h[7] = __half(0.0f);
    RecU rd;
    rd.h[0] = __float2half_rn(c0); rd.h[1] = __float2half_rn(c1);
    rd.h[2] = __float2half_rn(c2); rd.h[3] = __float2half_rn(c3);
    rd.h[4] = __float2half_rn(cq);
    rd.h[5] = __half(0.0f); rd.h[6] = __half(0.0f); rd.h[7] = __half(0.0f);
    srcRec[n] = rs.v;
    dstRec[n] = rd.v;
}

// Per-edge kernel, EPT edges/thread for MLP: batch all independent stream
// loads, then all gathers, then compute+store.
__global__ __launch_bounds__(256) void edge_k(
    const int* __restrict__ ei,
    const float* __restrict__ sf,
    const int* __restrict__ layer_idx_p,
    const float* __restrict__ gamma_h,
    const uint4* __restrict__ srcRec,
    const uint4* __restrict__ dstRec,
    float* __restrict__ out)
{
    __shared__ float s_g[HH];
    if (threadIdx.x < HH) {
        int li = layer_idx_p[0];
        s_g[threadIdx.x] = gamma_h[li * HH + threadIdx.x];
    }
    __syncthreads();

    int t = blockIdx.x * (256 * EPT) + threadIdx.x;

    int  rows[EPT], cols[EPT];
    v4f  f[EPT];
    bool valid[EPT];
#pragma unroll
    for (int k = 0; k < EPT; ++k) {
        int e = t + k * 256;
        valid[k] = (e < E_EDGES);
        if (valid[k]) {
            rows[k] = __builtin_nontemporal_load(ei + e);
            cols[k] = __builtin_nontemporal_load(ei + E_EDGES + e);
            f[k]    = __builtin_nontemporal_load((const v4f*)sf + e);
        }
    }

    RecU rs[EPT], rd[EPT];
#pragma unroll
    for (int k = 0; k < EPT; ++k) {
        if (valid[k]) {
            rs[k].v = srcRec[rows[k]];   // cached gather (L2-resident table)
            rd[k].v = dstRec[cols[k]];
        }
    }

#pragma unroll
    for (int k = 0; k < EPT; ++k) {
        if (!valid[k]) continue;
        float s = f[k].x * (__half2float(rs[k].h[0]) + __half2float(rd[k].h[0]))
                + f[k].y * (__half2float(rs[k].h[1]) + __half2float(rd[k].h[1]))
                + f[k].z * (__half2float(rs[k].h[2]) + __half2float(rd[k].h[2]))
                + f[k].w * (__half2float(rs[k].h[3]) + __half2float(rd[k].h[3]))
                + __half2float(rs[k].h[4]) + __half2float(rd[k].h[4]);
        float base = (s > 0.0f) ? s : 0.01f * s;

        int e = t + k * 256;
        v4f o0 = { s_g[0] * base, s_g[1] * base, s_g[2] * base, s_g[3] * base };
        v4f o1 = { s_g[4] * base, s_g[5] * base, s_g[6] * base, s_g[7] * base };
        v4f* op = (v4f*)(out + (size_t)e * HH);
        __builtin_nontemporal_store(o0, op);
        __builtin_nontemporal_store(o1, op + 1);
    }
}

extern "C" void kernel_launch(void* const* d_in, const int* in_sizes, int n_in,
                              void* d_out, int out_size, void* d_ws, size_t ws_size,
                              hipStream_t stream) {
    const float* x       = (const float*)d_in[0];
    const int*   ei      = (const int*)d_in[1];
    const float* sf      = (const float*)d_in[2];
    const int*   li      = (const int*)d_in[3];
    const float* psi_w   = (const float*)d_in[4];
    const float* psi_b   = (const float*)d_in[5];
    const float* delta_w = (const float*)d_in[6];
    const float* u       = (const float*)d_in[7];
    const float* gamma_h = (const float*)d_in[8];
    float* out = (float*)d_out;

    char* ws = (char*)d_ws;
    uint4* srcRec = (uint4*)(ws);                             // N*16 B
    uint4* dstRec = (uint4*)(ws + (size_t)N_NODES * 16);      // N*16 B (3.2 MB total)

    node_pre<<<(N_NODES + 255) / 256, 256, 0, stream>>>(
        x, li, psi_w, psi_b, delta_w, u, srcRec, dstRec);

    int edge_blocks = (E_EDGES + 256 * EPT - 1) / (256 * EPT);
    edge_k<<<edge_blocks, 256, 0, stream>>>(
        ei, sf, li, gamma_h, srcRec, dstRec, out);
}

// Round 6
// 144.237 us; speedup vs baseline: 1.0238x; 1.0238x over previous
//
#include <hip/hip_runtime.h>
#include <hip/hip_fp16.h>

#define N_NODES 100000
#define CCH 64
#define E_EDGES 1600000
#define HH 8
#define ETHR 1024   // edge-kernel block size: 16 waves/block, 2 blocks/CU -> 100% occupancy

typedef float v4f __attribute__((ext_vector_type(4)));

// Unified interleaved table: node n -> 32 B = [srcRec 16 B | dstRec 16 B].
// Each record: p[4], q as fp16 (+3 pad). Total 3.2 MB -> fits per-XCD 4 MiB L2.
union RecU {
    uint4  v;
    __half h[8];
};

__global__ __launch_bounds__(256) void node_pre(
    const float* __restrict__ x,
    const int* __restrict__ layer_idx_p,
    const float* __restrict__ psi_w,
    const float* __restrict__ psi_b,
    const float* __restrict__ delta_w,
    const float* __restrict__ u,
    uint4* __restrict__ recs)          // recs[2n] = src, recs[2n+1] = dst
{
    __shared__ float4 s_w0[CCH];
    __shared__ float4 s_w1[CCH];
    __shared__ float  s_b0[CCH];
    __shared__ float  s_b1[CCH];

    int li = layer_idx_p[0];
    for (int i = threadIdx.x; i < 2 * CCH; i += blockDim.x) {
        float4 w = make_float4(psi_w[i * 4 + 0], psi_w[i * 4 + 1],
                               psi_w[i * 4 + 2], psi_w[i * 4 + 3]);
        float bb = psi_b[i] + delta_w[li * 2 * CCH + i] + u[li * 2 * CCH + i];
        if (i < CCH) { s_w0[i] = w; s_b0[i] = bb; }
        else         { s_w1[i - CCH] = w; s_b1[i - CCH] = bb; }
    }
    __syncthreads();

    int n = blockIdx.x * blockDim.x + threadIdx.x;
    if (n >= N_NODES) return;

    const float4* xr = (const float4*)(x + (size_t)n * CCH);
    float a0 = 0, a1 = 0, a2 = 0, a3 = 0, aq = 0;
    float c0 = 0, c1 = 0, c2 = 0, c3 = 0, cq = 0;
#pragma unroll
    for (int it = 0; it < CCH / 4; ++it) {
        float4 xv4 = xr[it];
        float xv[4] = { xv4.x, xv4.y, xv4.z, xv4.w };
#pragma unroll
        for (int j = 0; j < 4; ++j) {
            int c = it * 4 + j;
            float xv_ = xv[j];
            float4 w0 = s_w0[c];
            float4 w1 = s_w1[c];
            a0 += xv_ * w0.x; a1 += xv_ * w0.y; a2 += xv_ * w0.z; a3 += xv_ * w0.w;
            aq += xv_ * s_b0[c];
            c0 += xv_ * w1.x; c1 += xv_ * w1.y; c2 += xv_ * w1.z; c3 += xv_ * w1.w;
            cq += xv_ * s_b1[c];
        }
    }
    RecU rs;
    rs.h[0] = __float2half_rn(a0); rs.h[1] = __float2half_rn(a1);
    rs.h[2] = __float2half_rn(a2); rs.h[3] = __float2half_rn(a3);
    rs.h[4] = __float2half_rn(aq);
    rs.h[5] = __half(0.0f); rs.h[6] = __half(0.0f); rs.h[7] = __half(0.0f);
    RecU rd;
    rd.h[0] = __float2half_rn(c0); rd.h[1] = __float2half_rn(c1);
    rd.h[2] = __float2half_rn(c2); rd.h[3] = __float2half_rn(c3);
    rd.h[4] = __float2half_rn(cq);
    rd.h[5] = __half(0.0f); rd.h[6] = __half(0.0f); rd.h[7] = __half(0.0f);
    recs[2 * (size_t)n]     = rs.v;
    recs[2 * (size_t)n + 1] = rd.v;
}

// Per-edge kernel. block=1024: VGPR=16 -> 2 blocks/CU co-resident = 32 waves/CU
// (100% occupancy; was 65.8% at block=256) -> deeper per-CU memory queues.
__global__ __launch_bounds__(ETHR) void edge_k(
    const int* __restrict__ ei,
    const float* __restrict__ sf,
    const int* __restrict__ layer_idx_p,
    const float* __restrict__ gamma_h,
    const uint4* __restrict__ recs,
    float* __restrict__ out)
{
    __shared__ float s_g[HH];
    if (threadIdx.x < HH) {
        int li = layer_idx_p[0];
        s_g[threadIdx.x] = gamma_h[li * HH + threadIdx.x];
    }
    __syncthreads();

    int e = blockIdx.x * ETHR + threadIdx.x;
    if (e >= E_EDGES) return;

    int row = __builtin_nontemporal_load(ei + e);
    int col = __builtin_nontemporal_load(ei + E_EDGES + e);
    v4f f   = __builtin_nontemporal_load((const v4f*)sf + e);

    RecU rs; rs.v = recs[2 * (size_t)row];       // src record of row
    RecU rd; rd.v = recs[2 * (size_t)col + 1];   // dst record of col

    float s = f.x * (__half2float(rs.h[0]) + __half2float(rd.h[0]))
            + f.y * (__half2float(rs.h[1]) + __half2float(rd.h[1]))
            + f.z * (__half2float(rs.h[2]) + __half2float(rd.h[2]))
            + f.w * (__half2float(rs.h[3]) + __half2float(rd.h[3]))
            + __half2float(rs.h[4]) + __half2float(rd.h[4]);
    float base = (s > 0.0f) ? s : 0.01f * s;

    v4f o0 = { s_g[0] * base, s_g[1] * base, s_g[2] * base, s_g[3] * base };
    v4f o1 = { s_g[4] * base, s_g[5] * base, s_g[6] * base, s_g[7] * base };
    v4f* op = (v4f*)(out + (size_t)e * HH);
    __builtin_nontemporal_store(o0, op);
    __builtin_nontemporal_store(o1, op + 1);
}

extern "C" void kernel_launch(void* const* d_in, const int* in_sizes, int n_in,
                              void* d_out, int out_size, void* d_ws, size_t ws_size,
                              hipStream_t stream) {
    const float* x       = (const float*)d_in[0];
    const int*   ei      = (const int*)d_in[1];
    const float* sf      = (const float*)d_in[2];
    const int*   li      = (const int*)d_in[3];
    const float* psi_w   = (const float*)d_in[4];
    const float* psi_b   = (const float*)d_in[5];
    const float* delta_w = (const float*)d_in[6];
    const float* u       = (const float*)d_in[7];
    const float* gamma_h = (const float*)d_in[8];
    float* out = (float*)d_out;

    uint4* recs = (uint4*)d_ws;   // 2 * N * 16 B = 3.2 MB interleaved table

    node_pre<<<(N_NODES + 255) / 256, 256, 0, stream>>>(
        x, li, psi_w, psi_b, delta_w, u, recs);

    edge_k<<<(E_EDGES + ETHR - 1) / ETHR, ETHR, 0, stream>>>(
        ei, sf, li, gamma_h, recs, out);
}